// Round 18
// baseline (307.581 us; speedup 1.0000x reference)
//
#include <hip/hip_runtime.h>
#include <hip/hip_bf16.h>

typedef __bf16 bf16;
typedef __attribute__((ext_vector_type(8))) __bf16 bf16x8;
typedef __attribute__((ext_vector_type(4))) float f32x4;

#define T_TOK 8192
#define DIN   4096
#define DOUT  4096
#define RNK   16
#define NS    16
#define KLORA (NS * RNK)   // 256
#define GATE  0.12f

typedef __attribute__((address_space(1))) const void gconst_t;
typedef __attribute__((address_space(3))) void lds_t;

__device__ __forceinline__ void gload_lds16(const void* g, void* l) {
  __builtin_amdgcn_global_load_lds((gconst_t*)g, (lds_t*)l, 16, 0, 0);
}

#define BAR() do { asm volatile("" ::: "memory"); \
                   __builtin_amdgcn_s_barrier();  \
                   asm volatile("" ::: "memory"); } while (0)
#define VMW(n) asm volatile("s_waitcnt vmcnt(" #n ")" ::: "memory")
#define LGKM(n) do { asm volatile("s_waitcnt lgkmcnt(" #n ")" ::: "memory"); \
                     __builtin_amdgcn_sched_barrier(0); } while (0)
#define SB0 __builtin_amdgcn_sched_barrier(0)
#define PRIO1 __builtin_amdgcn_s_setprio(1)
#define PRIO0 __builtin_amdgcn_s_setprio(0)

// ---------------------------------------------------------------- fused prep (role-split blocks)
__global__ __launch_bounds__(256)
void prep_all_kernel(const float* __restrict__ x, bf16* __restrict__ xb,
                     const float* __restrict__ B, const float* __restrict__ dw,
                     const int* __restrict__ sd, bf16* __restrict__ bg,
                     const float* __restrict__ A, bf16* __restrict__ at) {
  __shared__ float tl[32][33];
  const int bid = blockIdx.x;
  if (bid < 16384) {
    const long i = ((long)bid * 256 + threadIdx.x) * 8;
    const float4 v0 = *(const float4*)(x + i);
    const float4 v1 = *(const float4*)(x + i + 4);
    bf16x8 o;
    o[0] = (bf16)v0.x; o[1] = (bf16)v0.y; o[2] = (bf16)v0.z; o[3] = (bf16)v0.w;
    o[4] = (bf16)v1.x; o[5] = (bf16)v1.y; o[6] = (bf16)v1.z; o[7] = (bf16)v1.w;
    *(bf16x8*)(xb + i) = o;
  } else if (bid < 16384 + 4096) {
    const int t = (bid - 16384) * 256 + threadIdx.x;
    const int o = t >> 8, k = t & 255, s = k >> 4, r = k & 15;
    const float w = dw[sd[s]];
    const float g = (w > GATE) ? w : 0.f;
    bg[t] = (bf16)(g * B[((size_t)s * DOUT + o) * RNK + r]);
  } else {
    const int tb = bid - 16384 - 4096;       // 1024 tiles: 128 d-tiles x 8 k-tiles
    const int d0 = (tb & 127) * 32, k0 = (tb >> 7) * 32;
    const int tx = threadIdx.x & 31, ty = threadIdx.x >> 5;
#pragma unroll
    for (int i = 0; i < 32; i += 8)
      tl[ty + i][tx] = A[(size_t)(k0 + ty + i) * DIN + d0 + tx];
    __syncthreads();
#pragma unroll
    for (int i = 0; i < 32; i += 8)
      at[(size_t)(d0 + ty + i) * KLORA + k0 + tx] = (bf16)tl[tx][ty + i];
  }
}

// ---------------------------------------------------------------- 128^2 GEMM (W_eff only)
__global__ __launch_bounds__(256)
void gemm_bt(const bf16* __restrict__ Am, const bf16* __restrict__ Bm,
             const float* __restrict__ extra, bf16* __restrict__ outB,
             int M, int N, int K) {
  constexpr int BM = 128, BN = 128, BK = 32;
  __shared__ __align__(16) bf16 At[BM * BK];
  __shared__ __align__(16) bf16 Bt[BN * BK];

  const int tid  = threadIdx.x;
  const int wave = tid >> 6, lane = tid & 63;

  const int nwg = gridDim.x, bid = blockIdx.x;
  const int qq  = nwg >> 3;
  const int sw  = (bid & 7) * qq + (bid >> 3);
  const int ntN = N / BN;
  const long row0 = (long)(sw / ntN) * BM;
  const long col0 = (long)(sw % ntN) * BN;

  f32x4 acc[4][4] = {};
  const int kSteps = K / BK;

  auto stage = [&](int ks) {
    const long k0 = (long)ks * BK;
#pragma unroll
    for (int r = 0; r < 2; ++r) {
      const int off = tid * 16 + r * 4096;
      const int row = off >> 6;
      const int el  = (off & 63) >> 1;
      char* ldsA = (char*)At + (wave << 10) + (r << 12);
      char* ldsB = (char*)Bt + (wave << 10) + (r << 12);
      gload_lds16(Am + (row0 + row) * K + k0 + el, ldsA);
      gload_lds16(Bm + (col0 + row) * K + k0 + el, ldsB);
    }
  };

  stage(0);
  for (int ks = 0; ks < kSteps; ++ks) {
    __syncthreads();
    bf16x8 afr[4], bfr[4];
    const int koff = (lane >> 4) << 3;
    const int rsel = lane & 15;
    const int wr = wave >> 1, wc = wave & 1;
#pragma unroll
    for (int m = 0; m < 4; ++m)
      afr[m] = *(const bf16x8*)&At[((wr << 6) + (m << 4) + rsel) * BK + koff];
#pragma unroll
    for (int n = 0; n < 4; ++n)
      bfr[n] = *(const bf16x8*)&Bt[((wc << 6) + (n << 4) + rsel) * BK + koff];
    __syncthreads();
    if (ks + 1 < kSteps) stage(ks + 1);
#pragma unroll
    for (int m = 0; m < 4; ++m)
#pragma unroll
      for (int n = 0; n < 4; ++n)
        acc[m][n] = __builtin_amdgcn_mfma_f32_16x16x32_bf16(afr[m], bfr[n],
                                                            acc[m][n], 0, 0, 0);
  }

  const int wr = wave >> 1, wc = wave & 1;
#pragma unroll
  for (int m = 0; m < 4; ++m)
#pragma unroll
    for (int n = 0; n < 4; ++n)
#pragma unroll
      for (int j = 0; j < 4; ++j) {
        const long row = row0 + wr * 64 + m * 16 + ((lane >> 4) << 2) + j;
        const long col = col0 + wc * 64 + n * 16 + (lane & 15);
        outB[row * N + col] = (bf16)(acc[m][n][j] + extra[row * N + col]);
      }
}

// ---------------------------------------------------------------- 256^2 GEMM — row-half 8-phase (r17) + nt stores
// Half-tiles are ROW-halves at full BK=64: H = 4T + {0:A-lo,1:B-lo,2:A-hi,3:B-hi},
// slot = H&7 (16KB = 128 rows x 128B). Wave (wr,wc of 2Mx4N) reads FIXED slots:
// A-half = wr, B-half = wc>>1. 2 K-tiles/iteration, 8 phases, 2 BARs/phase.
// Stage cadence (WAR-safe, r17): ph1 -> Hb; ph2 -> none; ph3 -> Hb+2;
// ph4 -> Hb+1 + Hb+3; VMW(6) at ph4 only; VMW(0) on last iteration.
// r18: (1) lgkmcnt(8) after ph1's 12 ds_reads (m201 fidelity);
// (2) __builtin_nontemporal_store for the f32 output — the 128MB write-only
// stream was thrashing L3 (FETCH 295MB vs ~100MB ideal), causing staging
// gloads to miss to HBM and stall the counted vmcnt waits.
__global__ __launch_bounds__(512, 2)
void gemm256(const bf16* __restrict__ Am, const bf16* __restrict__ Bm,
             const float* __restrict__ bias, float* __restrict__ out,
             int M, int N, int K) {
  extern __shared__ char smem[];
  const int tid  = threadIdx.x;
  const int wave = tid >> 6, lane = tid & 63;
  const int wr = wave >> 2, wc = wave & 3;       // 2M x 4N wave grid
  const int rsel = lane & 15, klane = lane >> 4;

  const int nwg = gridDim.x, bid = blockIdx.x;   // nwg multiple of 8
  const int sw  = (bid & 7) * (nwg >> 3) + (bid >> 3);
  const int ntN = N >> 8;
  const long row0 = (long)(sw / ntN) << 8;
  const long col0 = (long)(sw % ntN) << 8;

  // staging: dest = slot*16KB + chunk*1024 (+ HW lane*16). chunk = wave*2+r.
  // stored elem k = ((lane&7)^((lane>>3)&7))*8  (swizzle kb ^= (row&7)<<4).
  long srcA[2], srcB[2];
  int  ldsd[2];
#pragma unroll
  for (int r = 0; r < 2; ++r) {
    const int chunk = wave * 2 + r;
    const int rowl  = chunk * 8 + (lane >> 3);
    const int kbe   = ((lane & 7) ^ ((lane >> 3) & 7)) << 3;   // elems
    srcA[r] = (row0 + rowl) * (long)K + kbe;
    srcB[r] = (col0 + rowl) * (long)K + kbe;
    ldsd[r] = chunk << 10;
  }

  const int nT = K >> 6;          // 64 K-tiles
  const int nIter = nT >> 1;      // 32 iterations

  auto stageH = [&](int H) {
    if (H >= 4 * nT) return;
    const int  slot = H & 7;
    const long ofs  = ((H & 2) ? 128L * K : 0L) + (long)(H >> 2) * 64;
    char* dst = smem + (slot << 14);
    if (H & 1) {
      gload_lds16(Bm + srcB[0] + ofs, dst + ldsd[0]);
      gload_lds16(Bm + srcB[1] + ofs, dst + ldsd[1]);
    } else {
      gload_lds16(Am + srcA[0] + ofs, dst + ldsd[0]);
      gload_lds16(Am + srcA[1] + ofs, dst + ldsd[1]);
    }
  };

  const int sAofs = 2 * wr;               // wave's A-half H-offset within a tile
  const int sBofs = 1 + 2 * (wc >> 1);    // wave's B-half H-offset
  const int brow  = (wc & 1) * 64;        // wave's 64-col window within B-half

  f32x4 acc[8][4] = {};
  bf16x8 afr[4][2];        // [mi][kst] — current mh's A frags
  bf16x8 bfr[2][2][2];     // [nh][ni][kst] — both B halves held across phases

#define RDA(T, mh, mi, kst) \
  afr[mi][kst] = *(const bf16x8*)(smem + ((((4 * (T)) + sAofs) & 7) << 14) \
      + ((mh) * 64 + (mi) * 16 + rsel) * 128 \
      + ((((kst) * 64) + klane * 16) ^ ((rsel & 7) << 4)))
#define RDB(T, nh, ni, kst) \
  bfr[nh][ni][kst] = *(const bf16x8*)(smem + ((((4 * (T)) + sBofs) & 7) << 14) \
      + (brow + (nh) * 32 + (ni) * 16 + rsel) * 128 \
      + ((((kst) * 64) + klane * 16) ^ ((rsel & 7) << 4)))
// quadrant (mh,nh): 16 MFMA, kst outer for dependency spacing
#define MQ(mh, nh) do { \
  _Pragma("unroll") for (int _k = 0; _k < 2; ++_k) \
    _Pragma("unroll") for (int _m = 0; _m < 4; ++_m) \
      _Pragma("unroll") for (int _n = 0; _n < 2; ++_n) \
        acc[(mh) * 4 + _m][(nh) * 2 + _n] = \
            __builtin_amdgcn_mfma_f32_16x16x32_bf16( \
                afr[_m][_k], bfr[nh][_n][_k], \
                acc[(mh) * 4 + _m][(nh) * 2 + _n], 0, 0, 0); \
} while (0)

  // prologue
  stageH(0); stageH(1); stageH(2); stageH(3);
  VMW(4);
  stageH(4); stageH(5); stageH(6);
  VMW(6);
  BAR();

  for (int u = 0; u < nIter; ++u) {
    const int Ta = 2 * u, Tb = 2 * u + 1;
    const int H0 = 8 * u;
    const bool lastIt = (u == nIter - 1);

#define TILE4(T, Hbase) do { \
    /* ph1: A(mh0) 8 + B(nh0) 4 reads; stage Hb; lgkm(8); MFMA Q(0,0) */ \
    RDA(T, 0, 0, 0); RDA(T, 0, 0, 1); RDA(T, 0, 1, 0); RDA(T, 0, 1, 1); \
    RDA(T, 0, 2, 0); RDA(T, 0, 2, 1); RDA(T, 0, 3, 0); RDA(T, 0, 3, 1); \
    RDB(T, 0, 0, 0); RDB(T, 0, 0, 1); RDB(T, 0, 1, 0); RDB(T, 0, 1, 1); \
    stageH((Hbase)); \
    LGKM(8); \
    BAR(); LGKM(0); \
    PRIO1; MQ(0, 0); PRIO0; \
    BAR(); \
    /* ph2: B(nh1) 4 reads; no stage; MFMA Q(0,1) */ \
    RDB(T, 1, 0, 0); RDB(T, 1, 0, 1); RDB(T, 1, 1, 0); RDB(T, 1, 1, 1); \
    BAR(); LGKM(0); \
    PRIO1; MQ(0, 1); PRIO0; \
    BAR(); \
    /* ph3: A(mh1) 8 reads; stage Hb+2 (B-lo slot; last read ph2) */ \
    RDA(T, 1, 0, 0); RDA(T, 1, 0, 1); RDA(T, 1, 1, 0); RDA(T, 1, 1, 1); \
    RDA(T, 1, 2, 0); RDA(T, 1, 2, 1); RDA(T, 1, 3, 0); RDA(T, 1, 3, 1); \
    stageH((Hbase) + 2); \
    BAR(); LGKM(0); \
    PRIO1; MQ(1, 0); PRIO0; \
    BAR(); \
    /* ph4: 0 reads; stage Hb+1, Hb+3 (A-slots; last read ph3); retire */ \
    stageH((Hbase) + 1); stageH((Hbase) + 3); \
    BAR(); \
    PRIO1; MQ(1, 1); PRIO0; \
    if (lastIt) { VMW(0); } else { VMW(6); } \
    BAR(); \
} while (0)

    TILE4(Ta, H0 + 7);
    TILE4(Tb, H0 + 11);
#undef TILE4
  }

#undef RDA
#undef RDB
#undef MQ

  // epilogue — C/D layout: col = lane&15, row = (lane>>4)*4 + j.
  // Non-temporal stores: out is a write-only 128MB stream; keep it out of L3
  // so xb/weff stay resident for the staging loads.
#pragma unroll
  for (int am = 0; am < 8; ++am)
#pragma unroll
    for (int an = 0; an < 4; ++an)
#pragma unroll
      for (int j = 0; j < 4; ++j) {
        const long row = row0 + wr * 128 + am * 16 + klane * 4 + j;
        const long col = col0 + wc * 64 + an * 16 + rsel;
        __builtin_nontemporal_store(acc[am][an][j] + bias[col],
                                    &out[row * N + col]);
      }
}

// ---------------------------------------------------------------- launch

extern "C" void kernel_launch(void* const* d_in, const int* in_sizes, int n_in,
                              void* d_out, int out_size, void* d_ws, size_t ws_size,
                              hipStream_t stream) {
  (void)in_sizes; (void)n_in; (void)out_size; (void)ws_size;
  const float* x  = (const float*)d_in[0];
  const float* W  = (const float*)d_in[1];
  const float* b  = (const float*)d_in[2];
  const float* A  = (const float*)d_in[3];
  const float* B  = (const float*)d_in[4];
  const float* dw = (const float*)d_in[5];
  const int*   sd = (const int*)d_in[6];
  float* out = (float*)d_out;

  char* ws = (char*)d_ws;
  bf16* xb    = (bf16*)(ws);                          // 64 MB
  bf16* weff  = (bf16*)(ws + ((size_t)64 << 20));     // 32 MB
  bf16* bg    = (bf16*)(ws + ((size_t)96 << 20));     //  2 MB
  bf16* acatT = (bf16*)(ws + ((size_t)98 << 20));     //  2 MB

  // 1) fused memory-bound prep: x-cast | Bg | A^T
  prep_all_kernel<<<16384 + 4096 + 1024, 256, 0, stream>>>(
      x, xb, B, dw, sd, bg, A, acatT);

  // 2) W_eff = bf16(W + Bg @ AcatT^T)   : M=DOUT, N=DIN, K=256
  gemm_bt<<<(DOUT / 128) * (DIN / 128), 256, 0, stream>>>(
      bg, acatT, W, weff, DOUT, DIN, KLORA);

  // 3) out = xb @ W_eff^T + b           : M=T, N=DOUT, K=DIN
  static_assert((T_TOK % 256) == 0 && (DOUT % 256) == 0 && (DIN % 128) == 0, "");
  hipFuncSetAttribute(reinterpret_cast<const void*>(gemm256),
                      hipFuncAttributeMaxDynamicSharedMemorySize, 131072);
  gemm256<<<(T_TOK / 256) * (DOUT / 256), 512, 131072, stream>>>(
      xb, weff, b, out, T_TOK, DOUT, DIN);
}

// Round 19
// 305.817 us; speedup vs baseline: 1.0058x; 1.0058x over previous
//
#include <hip/hip_runtime.h>
#include <hip/hip_bf16.h>

typedef __bf16 bf16;
typedef __attribute__((ext_vector_type(8))) __bf16 bf16x8;
typedef __attribute__((ext_vector_type(4))) float f32x4;

#define T_TOK 8192
#define DIN   4096
#define DOUT  4096
#define RNK   16
#define NS    16
#define KLORA (NS * RNK)   // 256
#define GATE  0.12f

typedef __attribute__((address_space(1))) const void gconst_t;
typedef __attribute__((address_space(3))) void lds_t;

__device__ __forceinline__ void gload_lds16(const void* g, void* l) {
  __builtin_amdgcn_global_load_lds((gconst_t*)g, (lds_t*)l, 16, 0, 0);
}

#define BAR() do { asm volatile("" ::: "memory"); \
                   __builtin_amdgcn_s_barrier();  \
                   asm volatile("" ::: "memory"); } while (0)
#define VMW(n) asm volatile("s_waitcnt vmcnt(" #n ")" ::: "memory")
#define LGKM(n) do { asm volatile("s_waitcnt lgkmcnt(" #n ")" ::: "memory"); \
                     __builtin_amdgcn_sched_barrier(0); } while (0)
#define SB0 __builtin_amdgcn_sched_barrier(0)
#define PRIO1 __builtin_amdgcn_s_setprio(1)
#define PRIO0 __builtin_amdgcn_s_setprio(0)

// ---------------------------------------------------------------- fused prep (role-split blocks)
__global__ __launch_bounds__(256)
void prep_all_kernel(const float* __restrict__ x, bf16* __restrict__ xb,
                     const float* __restrict__ B, const float* __restrict__ dw,
                     const int* __restrict__ sd, bf16* __restrict__ bg,
                     const float* __restrict__ A, bf16* __restrict__ at) {
  __shared__ float tl[32][33];
  const int bid = blockIdx.x;
  if (bid < 16384) {
    const long i = ((long)bid * 256 + threadIdx.x) * 8;
    const float4 v0 = *(const float4*)(x + i);
    const float4 v1 = *(const float4*)(x + i + 4);
    bf16x8 o;
    o[0] = (bf16)v0.x; o[1] = (bf16)v0.y; o[2] = (bf16)v0.z; o[3] = (bf16)v0.w;
    o[4] = (bf16)v1.x; o[5] = (bf16)v1.y; o[6] = (bf16)v1.z; o[7] = (bf16)v1.w;
    *(bf16x8*)(xb + i) = o;
  } else if (bid < 16384 + 4096) {
    const int t = (bid - 16384) * 256 + threadIdx.x;
    const int o = t >> 8, k = t & 255, s = k >> 4, r = k & 15;
    const float w = dw[sd[s]];
    const float g = (w > GATE) ? w : 0.f;
    bg[t] = (bf16)(g * B[((size_t)s * DOUT + o) * RNK + r]);
  } else {
    const int tb = bid - 16384 - 4096;       // 1024 tiles: 128 d-tiles x 8 k-tiles
    const int d0 = (tb & 127) * 32, k0 = (tb >> 7) * 32;
    const int tx = threadIdx.x & 31, ty = threadIdx.x >> 5;
#pragma unroll
    for (int i = 0; i < 32; i += 8)
      tl[ty + i][tx] = A[(size_t)(k0 + ty + i) * DIN + d0 + tx];
    __syncthreads();
#pragma unroll
    for (int i = 0; i < 32; i += 8)
      at[(size_t)(d0 + ty + i) * KLORA + k0 + tx] = (bf16)tl[tx][ty + i];
  }
}

// ---------------------------------------------------------------- 128^2 GEMM (W_eff only)
__global__ __launch_bounds__(256)
void gemm_bt(const bf16* __restrict__ Am, const bf16* __restrict__ Bm,
             const float* __restrict__ extra, bf16* __restrict__ outB,
             int M, int N, int K) {
  constexpr int BM = 128, BN = 128, BK = 32;
  __shared__ __align__(16) bf16 At[BM * BK];
  __shared__ __align__(16) bf16 Bt[BN * BK];

  const int tid  = threadIdx.x;
  const int wave = tid >> 6, lane = tid & 63;

  const int nwg = gridDim.x, bid = blockIdx.x;
  const int qq  = nwg >> 3;
  const int sw  = (bid & 7) * qq + (bid >> 3);
  const int ntN = N / BN;
  const long row0 = (long)(sw / ntN) * BM;
  const long col0 = (long)(sw % ntN) * BN;

  f32x4 acc[4][4] = {};
  const int kSteps = K / BK;

  auto stage = [&](int ks) {
    const long k0 = (long)ks * BK;
#pragma unroll
    for (int r = 0; r < 2; ++r) {
      const int off = tid * 16 + r * 4096;
      const int row = off >> 6;
      const int el  = (off & 63) >> 1;
      char* ldsA = (char*)At + (wave << 10) + (r << 12);
      char* ldsB = (char*)Bt + (wave << 10) + (r << 12);
      gload_lds16(Am + (row0 + row) * K + k0 + el, ldsA);
      gload_lds16(Bm + (col0 + row) * K + k0 + el, ldsB);
    }
  };

  stage(0);
  for (int ks = 0; ks < kSteps; ++ks) {
    __syncthreads();
    bf16x8 afr[4], bfr[4];
    const int koff = (lane >> 4) << 3;
    const int rsel = lane & 15;
    const int wr = wave >> 1, wc = wave & 1;
#pragma unroll
    for (int m = 0; m < 4; ++m)
      afr[m] = *(const bf16x8*)&At[((wr << 6) + (m << 4) + rsel) * BK + koff];
#pragma unroll
    for (int n = 0; n < 4; ++n)
      bfr[n] = *(const bf16x8*)&Bt[((wc << 6) + (n << 4) + rsel) * BK + koff];
    __syncthreads();
    if (ks + 1 < kSteps) stage(ks + 1);
#pragma unroll
    for (int m = 0; m < 4; ++m)
#pragma unroll
      for (int n = 0; n < 4; ++n)
        acc[m][n] = __builtin_amdgcn_mfma_f32_16x16x32_bf16(afr[m], bfr[n],
                                                            acc[m][n], 0, 0, 0);
  }

  const int wr = wave >> 1, wc = wave & 1;
#pragma unroll
  for (int m = 0; m < 4; ++m)
#pragma unroll
    for (int n = 0; n < 4; ++n)
#pragma unroll
      for (int j = 0; j < 4; ++j) {
        const long row = row0 + wr * 64 + m * 16 + ((lane >> 4) << 2) + j;
        const long col = col0 + wc * 64 + n * 16 + (lane & 15);
        outB[row * N + col] = (bf16)(acc[m][n][j] + extra[row * N + col]);
      }
}

// ---------------------------------------------------------------- 256^2 GEMM — row-half 8-phase (r17, best measured)
// Half-tiles are ROW-halves at full BK=64: H = 4T + {0:A-lo,1:B-lo,2:A-hi,3:B-hi},
// slot = H&7 (16KB = 128 rows x 128B). Wave (wr,wc of 2Mx4N) reads FIXED slots:
// A-half = wr, B-half = wc>>1. 2 K-tiles/iteration, 8 phases, 2 BARs/phase.
// Stage cadence (WAR-safe): ph1 -> Hb; ph2 -> none; ph3 -> Hb+2;
// ph4 -> Hb+1 + Hb+3; VMW(6) at ph4 only; VMW(0) on last iteration.
__global__ __launch_bounds__(512, 2)
void gemm256(const bf16* __restrict__ Am, const bf16* __restrict__ Bm,
             const float* __restrict__ bias, float* __restrict__ out,
             int M, int N, int K) {
  extern __shared__ char smem[];
  const int tid  = threadIdx.x;
  const int wave = tid >> 6, lane = tid & 63;
  const int wr = wave >> 2, wc = wave & 3;       // 2M x 4N wave grid
  const int rsel = lane & 15, klane = lane >> 4;

  const int nwg = gridDim.x, bid = blockIdx.x;   // nwg multiple of 8
  const int sw  = (bid & 7) * (nwg >> 3) + (bid >> 3);
  const int ntN = N >> 8;
  const long row0 = (long)(sw / ntN) << 8;
  const long col0 = (long)(sw % ntN) << 8;

  // staging: dest = slot*16KB + chunk*1024 (+ HW lane*16). chunk = wave*2+r.
  // stored elem k = ((lane&7)^((lane>>3)&7))*8  (swizzle kb ^= (row&7)<<4).
  long srcA[2], srcB[2];
  int  ldsd[2];
#pragma unroll
  for (int r = 0; r < 2; ++r) {
    const int chunk = wave * 2 + r;
    const int rowl  = chunk * 8 + (lane >> 3);
    const int kbe   = ((lane & 7) ^ ((lane >> 3) & 7)) << 3;   // elems
    srcA[r] = (row0 + rowl) * (long)K + kbe;
    srcB[r] = (col0 + rowl) * (long)K + kbe;
    ldsd[r] = chunk << 10;
  }

  const int nT = K >> 6;          // 64 K-tiles
  const int nIter = nT >> 1;      // 32 iterations

  auto stageH = [&](int H) {
    if (H >= 4 * nT) return;
    const int  slot = H & 7;
    const long ofs  = ((H & 2) ? 128L * K : 0L) + (long)(H >> 2) * 64;
    char* dst = smem + (slot << 14);
    if (H & 1) {
      gload_lds16(Bm + srcB[0] + ofs, dst + ldsd[0]);
      gload_lds16(Bm + srcB[1] + ofs, dst + ldsd[1]);
    } else {
      gload_lds16(Am + srcA[0] + ofs, dst + ldsd[0]);
      gload_lds16(Am + srcA[1] + ofs, dst + ldsd[1]);
    }
  };

  const int sAofs = 2 * wr;               // wave's A-half H-offset within a tile
  const int sBofs = 1 + 2 * (wc >> 1);    // wave's B-half H-offset
  const int brow  = (wc & 1) * 64;        // wave's 64-col window within B-half

  f32x4 acc[8][4] = {};
  bf16x8 afr[4][2];        // [mi][kst] — current mh's A frags
  bf16x8 bfr[2][2][2];     // [nh][ni][kst] — both B halves held across phases

#define RDA(T, mh, mi, kst) \
  afr[mi][kst] = *(const bf16x8*)(smem + ((((4 * (T)) + sAofs) & 7) << 14) \
      + ((mh) * 64 + (mi) * 16 + rsel) * 128 \
      + ((((kst) * 64) + klane * 16) ^ ((rsel & 7) << 4)))
#define RDB(T, nh, ni, kst) \
  bfr[nh][ni][kst] = *(const bf16x8*)(smem + ((((4 * (T)) + sBofs) & 7) << 14) \
      + (brow + (nh) * 32 + (ni) * 16 + rsel) * 128 \
      + ((((kst) * 64) + klane * 16) ^ ((rsel & 7) << 4)))
// quadrant (mh,nh): 16 MFMA, kst outer for dependency spacing
#define MQ(mh, nh) do { \
  _Pragma("unroll") for (int _k = 0; _k < 2; ++_k) \
    _Pragma("unroll") for (int _m = 0; _m < 4; ++_m) \
      _Pragma("unroll") for (int _n = 0; _n < 2; ++_n) \
        acc[(mh) * 4 + _m][(nh) * 2 + _n] = \
            __builtin_amdgcn_mfma_f32_16x16x32_bf16( \
                afr[_m][_k], bfr[nh][_n][_k], \
                acc[(mh) * 4 + _m][(nh) * 2 + _n], 0, 0, 0); \
} while (0)

  // prologue
  stageH(0); stageH(1); stageH(2); stageH(3);
  VMW(4);
  stageH(4); stageH(5); stageH(6);
  VMW(6);
  BAR();

  for (int u = 0; u < nIter; ++u) {
    const int Ta = 2 * u, Tb = 2 * u + 1;
    const int H0 = 8 * u;
    const bool lastIt = (u == nIter - 1);

#define TILE4(T, Hbase) do { \
    /* ph1: A(mh0) 8 + B(nh0) 4 reads; stage Hb; MFMA Q(0,0) */ \
    RDA(T, 0, 0, 0); RDA(T, 0, 0, 1); RDA(T, 0, 1, 0); RDA(T, 0, 1, 1); \
    RDA(T, 0, 2, 0); RDA(T, 0, 2, 1); RDA(T, 0, 3, 0); RDA(T, 0, 3, 1); \
    RDB(T, 0, 0, 0); RDB(T, 0, 0, 1); RDB(T, 0, 1, 0); RDB(T, 0, 1, 1); \
    stageH((Hbase)); \
    BAR(); LGKM(0); \
    PRIO1; MQ(0, 0); PRIO0; \
    BAR(); \
    /* ph2: B(nh1) 4 reads; no stage; MFMA Q(0,1) */ \
    RDB(T, 1, 0, 0); RDB(T, 1, 0, 1); RDB(T, 1, 1, 0); RDB(T, 1, 1, 1); \
    BAR(); LGKM(0); \
    PRIO1; MQ(0, 1); PRIO0; \
    BAR(); \
    /* ph3: A(mh1) 8 reads; stage Hb+2 (B-lo slot; last read ph2) */ \
    RDA(T, 1, 0, 0); RDA(T, 1, 0, 1); RDA(T, 1, 1, 0); RDA(T, 1, 1, 1); \
    RDA(T, 1, 2, 0); RDA(T, 1, 2, 1); RDA(T, 1, 3, 0); RDA(T, 1, 3, 1); \
    stageH((Hbase) + 2); \
    BAR(); LGKM(0); \
    PRIO1; MQ(1, 0); PRIO0; \
    BAR(); \
    /* ph4: 0 reads; stage Hb+1, Hb+3 (A-slots; last read ph3); retire */ \
    stageH((Hbase) + 1); stageH((Hbase) + 3); \
    BAR(); \
    PRIO1; MQ(1, 1); PRIO0; \
    if (lastIt) { VMW(0); } else { VMW(6); } \
    BAR(); \
} while (0)

    TILE4(Ta, H0 + 7);
    TILE4(Tb, H0 + 11);
#undef TILE4
  }

#undef RDA
#undef RDB
#undef MQ

  // epilogue — C/D layout: col = lane&15, row = (lane>>4)*4 + j
#pragma unroll
  for (int am = 0; am < 8; ++am)
#pragma unroll
    for (int an = 0; an < 4; ++an)
#pragma unroll
      for (int j = 0; j < 4; ++j) {
        const long row = row0 + wr * 128 + am * 16 + klane * 4 + j;
        const long col = col0 + wc * 64 + an * 16 + rsel;
        out[row * N + col] = acc[am][an][j] + bias[col];
      }
}

// ---------------------------------------------------------------- launch

extern "C" void kernel_launch(void* const* d_in, const int* in_sizes, int n_in,
                              void* d_out, int out_size, void* d_ws, size_t ws_size,
                              hipStream_t stream) {
  (void)in_sizes; (void)n_in; (void)out_size; (void)ws_size;
  const float* x  = (const float*)d_in[0];
  const float* W  = (const float*)d_in[1];
  const float* b  = (const float*)d_in[2];
  const float* A  = (const float*)d_in[3];
  const float* B  = (const float*)d_in[4];
  const float* dw = (const float*)d_in[5];
  const int*   sd = (const int*)d_in[6];
  float* out = (float*)d_out;

  char* ws = (char*)d_ws;
  bf16* xb    = (bf16*)(ws);                          // 64 MB
  bf16* weff  = (bf16*)(ws + ((size_t)64 << 20));     // 32 MB
  bf16* bg    = (bf16*)(ws + ((size_t)96 << 20));     //  2 MB
  bf16* acatT = (bf16*)(ws + ((size_t)98 << 20));     //  2 MB

  // 1) fused memory-bound prep: x-cast | Bg | A^T
  prep_all_kernel<<<16384 + 4096 + 1024, 256, 0, stream>>>(
      x, xb, B, dw, sd, bg, A, acatT);

  // 2) W_eff = bf16(W + Bg @ AcatT^T)   : M=DOUT, N=DIN, K=256
  gemm_bt<<<(DOUT / 128) * (DIN / 128), 256, 0, stream>>>(
      bg, acatT, W, weff, DOUT, DIN, KLORA);

  // 3) out = xb @ W_eff^T + b           : M=T, N=DOUT, K=DIN
  static_assert((T_TOK % 256) == 0 && (DOUT % 256) == 0 && (DIN % 128) == 0, "");
  hipFuncSetAttribute(reinterpret_cast<const void*>(gemm256),
                      hipFuncAttributeMaxDynamicSharedMemorySize, 131072);
  gemm256<<<(T_TOK / 256) * (DOUT / 256), 512, 131072, stream>>>(
      xb, weff, b, out, T_TOK, DOUT, DIN);
}

// Round 20
// 304.658 us; speedup vs baseline: 1.0096x; 1.0038x over previous
//
#include <hip/hip_runtime.h>
#include <hip/hip_bf16.h>

typedef __bf16 bf16;
typedef __attribute__((ext_vector_type(8))) __bf16 bf16x8;
typedef __attribute__((ext_vector_type(4))) float f32x4;

#define T_TOK 8192
#define DIN   4096
#define DOUT  4096
#define RNK   16
#define NS    16
#define KLORA (NS * RNK)   // 256
#define GATE  0.12f

typedef __attribute__((address_space(1))) const void gconst_t;
typedef __attribute__((address_space(3))) void lds_t;

__device__ __forceinline__ void gload_lds16(const void* g, void* l) {
  __builtin_amdgcn_global_load_lds((gconst_t*)g, (lds_t*)l, 16, 0, 0);
}

#define BAR() do { asm volatile("" ::: "memory"); \
                   __builtin_amdgcn_s_barrier();  \
                   asm volatile("" ::: "memory"); } while (0)
#define VMW(n) asm volatile("s_waitcnt vmcnt(" #n ")" ::: "memory")
#define LGKM(n) do { asm volatile("s_waitcnt lgkmcnt(" #n ")" ::: "memory"); \
                     __builtin_amdgcn_sched_barrier(0); } while (0)
#define SB0 __builtin_amdgcn_sched_barrier(0)
#define PRIO1 __builtin_amdgcn_s_setprio(1)
#define PRIO0 __builtin_amdgcn_s_setprio(0)

// ---------------------------------------------------------------- fused prep (role-split blocks)
__global__ __launch_bounds__(256)
void prep_all_kernel(const float* __restrict__ x, bf16* __restrict__ xb,
                     const float* __restrict__ B, const float* __restrict__ dw,
                     const int* __restrict__ sd, bf16* __restrict__ bg,
                     const float* __restrict__ A, bf16* __restrict__ at) {
  __shared__ float tl[32][33];
  const int bid = blockIdx.x;
  if (bid < 16384) {
    const long i = ((long)bid * 256 + threadIdx.x) * 8;
    const float4 v0 = *(const float4*)(x + i);
    const float4 v1 = *(const float4*)(x + i + 4);
    bf16x8 o;
    o[0] = (bf16)v0.x; o[1] = (bf16)v0.y; o[2] = (bf16)v0.z; o[3] = (bf16)v0.w;
    o[4] = (bf16)v1.x; o[5] = (bf16)v1.y; o[6] = (bf16)v1.z; o[7] = (bf16)v1.w;
    *(bf16x8*)(xb + i) = o;
  } else if (bid < 16384 + 4096) {
    const int t = (bid - 16384) * 256 + threadIdx.x;
    const int o = t >> 8, k = t & 255, s = k >> 4, r = k & 15;
    const float w = dw[sd[s]];
    const float g = (w > GATE) ? w : 0.f;
    bg[t] = (bf16)(g * B[((size_t)s * DOUT + o) * RNK + r]);
  } else {
    const int tb = bid - 16384 - 4096;       // 1024 tiles: 128 d-tiles x 8 k-tiles
    const int d0 = (tb & 127) * 32, k0 = (tb >> 7) * 32;
    const int tx = threadIdx.x & 31, ty = threadIdx.x >> 5;
#pragma unroll
    for (int i = 0; i < 32; i += 8)
      tl[ty + i][tx] = A[(size_t)(k0 + ty + i) * DIN + d0 + tx];
    __syncthreads();
#pragma unroll
    for (int i = 0; i < 32; i += 8)
      at[(size_t)(d0 + ty + i) * KLORA + k0 + tx] = (bf16)tl[tx][ty + i];
  }
}

// ---------------------------------------------------------------- 128^2 GEMM (W_eff only)
__global__ __launch_bounds__(256)
void gemm_bt(const bf16* __restrict__ Am, const bf16* __restrict__ Bm,
             const float* __restrict__ extra, bf16* __restrict__ outB,
             int M, int N, int K) {
  constexpr int BM = 128, BN = 128, BK = 32;
  __shared__ __align__(16) bf16 At[BM * BK];
  __shared__ __align__(16) bf16 Bt[BN * BK];

  const int tid  = threadIdx.x;
  const int wave = tid >> 6, lane = tid & 63;

  const int nwg = gridDim.x, bid = blockIdx.x;
  const int qq  = nwg >> 3;
  const int sw  = (bid & 7) * qq + (bid >> 3);
  const int ntN = N / BN;
  const long row0 = (long)(sw / ntN) * BM;
  const long col0 = (long)(sw % ntN) * BN;

  f32x4 acc[4][4] = {};
  const int kSteps = K / BK;

  auto stage = [&](int ks) {
    const long k0 = (long)ks * BK;
#pragma unroll
    for (int r = 0; r < 2; ++r) {
      const int off = tid * 16 + r * 4096;
      const int row = off >> 6;
      const int el  = (off & 63) >> 1;
      char* ldsA = (char*)At + (wave << 10) + (r << 12);
      char* ldsB = (char*)Bt + (wave << 10) + (r << 12);
      gload_lds16(Am + (row0 + row) * K + k0 + el, ldsA);
      gload_lds16(Bm + (col0 + row) * K + k0 + el, ldsB);
    }
  };

  stage(0);
  for (int ks = 0; ks < kSteps; ++ks) {
    __syncthreads();
    bf16x8 afr[4], bfr[4];
    const int koff = (lane >> 4) << 3;
    const int rsel = lane & 15;
    const int wr = wave >> 1, wc = wave & 1;
#pragma unroll
    for (int m = 0; m < 4; ++m)
      afr[m] = *(const bf16x8*)&At[((wr << 6) + (m << 4) + rsel) * BK + koff];
#pragma unroll
    for (int n = 0; n < 4; ++n)
      bfr[n] = *(const bf16x8*)&Bt[((wc << 6) + (n << 4) + rsel) * BK + koff];
    __syncthreads();
    if (ks + 1 < kSteps) stage(ks + 1);
#pragma unroll
    for (int m = 0; m < 4; ++m)
#pragma unroll
      for (int n = 0; n < 4; ++n)
        acc[m][n] = __builtin_amdgcn_mfma_f32_16x16x32_bf16(afr[m], bfr[n],
                                                            acc[m][n], 0, 0, 0);
  }

  const int wr = wave >> 1, wc = wave & 1;
#pragma unroll
  for (int m = 0; m < 4; ++m)
#pragma unroll
    for (int n = 0; n < 4; ++n)
#pragma unroll
      for (int j = 0; j < 4; ++j) {
        const long row = row0 + wr * 64 + m * 16 + ((lane >> 4) << 2) + j;
        const long col = col0 + wc * 64 + n * 16 + (lane & 15);
        outB[row * N + col] = (bf16)(acc[m][n][j] + extra[row * N + col]);
      }
}

// ---------------------------------------------------------------- 256^2 GEMM — row-half 8-phase (best measured)
// Half-tiles are ROW-halves at full BK=64: H = 4T + {0:A-lo,1:B-lo,2:A-hi,3:B-hi},
// slot = H&7 (16KB = 128 rows x 128B). Wave (wr,wc of 2Mx4N) reads FIXED slots:
// A-half = wr, B-half = wc>>1. 2 K-tiles/iteration, 8 phases, 2 BARs/phase.
// Stage cadence (WAR-safe): ph1 -> Hb; ph2 -> none; ph3 -> Hb+2;
// ph4 -> Hb+1 + Hb+3; VMW(6) at ph4 only; VMW(0) on last iteration.
__global__ __launch_bounds__(512, 2)
void gemm256(const bf16* __restrict__ Am, const bf16* __restrict__ Bm,
             const float* __restrict__ bias, float* __restrict__ out,
             int M, int N, int K) {
  extern __shared__ char smem[];
  const int tid  = threadIdx.x;
  const int wave = tid >> 6, lane = tid & 63;
  const int wr = wave >> 2, wc = wave & 3;       // 2M x 4N wave grid
  const int rsel = lane & 15, klane = lane >> 4;

  const int nwg = gridDim.x, bid = blockIdx.x;   // nwg multiple of 8
  const int sw  = (bid & 7) * (nwg >> 3) + (bid >> 3);
  const int ntN = N >> 8;
  const long row0 = (long)(sw / ntN) << 8;
  const long col0 = (long)(sw % ntN) << 8;

  // staging: dest = slot*16KB + chunk*1024 (+ HW lane*16). chunk = wave*2+r.
  // stored elem k = ((lane&7)^((lane>>3)&7))*8  (swizzle kb ^= (row&7)<<4).
  long srcA[2], srcB[2];
  int  ldsd[2];
#pragma unroll
  for (int r = 0; r < 2; ++r) {
    const int chunk = wave * 2 + r;
    const int rowl  = chunk * 8 + (lane >> 3);
    const int kbe   = ((lane & 7) ^ ((lane >> 3) & 7)) << 3;   // elems
    srcA[r] = (row0 + rowl) * (long)K + kbe;
    srcB[r] = (col0 + rowl) * (long)K + kbe;
    ldsd[r] = chunk << 10;
  }

  const int nT = K >> 6;          // 64 K-tiles
  const int nIter = nT >> 1;      // 32 iterations

  auto stageH = [&](int H) {
    if (H >= 4 * nT) return;
    const int  slot = H & 7;
    const long ofs  = ((H & 2) ? 128L * K : 0L) + (long)(H >> 2) * 64;
    char* dst = smem + (slot << 14);
    if (H & 1) {
      gload_lds16(Bm + srcB[0] + ofs, dst + ldsd[0]);
      gload_lds16(Bm + srcB[1] + ofs, dst + ldsd[1]);
    } else {
      gload_lds16(Am + srcA[0] + ofs, dst + ldsd[0]);
      gload_lds16(Am + srcA[1] + ofs, dst + ldsd[1]);
    }
  };

  const int sAofs = 2 * wr;               // wave's A-half H-offset within a tile
  const int sBofs = 1 + 2 * (wc >> 1);    // wave's B-half H-offset
  const int brow  = (wc & 1) * 64;        // wave's 64-col window within B-half

  f32x4 acc[8][4] = {};
  bf16x8 afr[4][2];        // [mi][kst] — current mh's A frags
  bf16x8 bfr[2][2][2];     // [nh][ni][kst] — both B halves held across phases

#define RDA(T, mh, mi, kst) \
  afr[mi][kst] = *(const bf16x8*)(smem + ((((4 * (T)) + sAofs) & 7) << 14) \
      + ((mh) * 64 + (mi) * 16 + rsel) * 128 \
      + ((((kst) * 64) + klane * 16) ^ ((rsel & 7) << 4)))
#define RDB(T, nh, ni, kst) \
  bfr[nh][ni][kst] = *(const bf16x8*)(smem + ((((4 * (T)) + sBofs) & 7) << 14) \
      + (brow + (nh) * 32 + (ni) * 16 + rsel) * 128 \
      + ((((kst) * 64) + klane * 16) ^ ((rsel & 7) << 4)))
// quadrant (mh,nh): 16 MFMA, kst outer for dependency spacing
#define MQ(mh, nh) do { \
  _Pragma("unroll") for (int _k = 0; _k < 2; ++_k) \
    _Pragma("unroll") for (int _m = 0; _m < 4; ++_m) \
      _Pragma("unroll") for (int _n = 0; _n < 2; ++_n) \
        acc[(mh) * 4 + _m][(nh) * 2 + _n] = \
            __builtin_amdgcn_mfma_f32_16x16x32_bf16( \
                afr[_m][_k], bfr[nh][_n][_k], \
                acc[(mh) * 4 + _m][(nh) * 2 + _n], 0, 0, 0); \
} while (0)

  // prologue
  stageH(0); stageH(1); stageH(2); stageH(3);
  VMW(4);
  stageH(4); stageH(5); stageH(6);
  VMW(6);
  BAR();

  for (int u = 0; u < nIter; ++u) {
    const int Ta = 2 * u, Tb = 2 * u + 1;
    const int H0 = 8 * u;
    const bool lastIt = (u == nIter - 1);

#define TILE4(T, Hbase) do { \
    /* ph1: A(mh0) 8 + B(nh0) 4 reads; stage Hb; MFMA Q(0,0) */ \
    RDA(T, 0, 0, 0); RDA(T, 0, 0, 1); RDA(T, 0, 1, 0); RDA(T, 0, 1, 1); \
    RDA(T, 0, 2, 0); RDA(T, 0, 2, 1); RDA(T, 0, 3, 0); RDA(T, 0, 3, 1); \
    RDB(T, 0, 0, 0); RDB(T, 0, 0, 1); RDB(T, 0, 1, 0); RDB(T, 0, 1, 1); \
    stageH((Hbase)); \
    BAR(); LGKM(0); \
    PRIO1; MQ(0, 0); PRIO0; \
    BAR(); \
    /* ph2: B(nh1) 4 reads; no stage; MFMA Q(0,1) */ \
    RDB(T, 1, 0, 0); RDB(T, 1, 0, 1); RDB(T, 1, 1, 0); RDB(T, 1, 1, 1); \
    BAR(); LGKM(0); \
    PRIO1; MQ(0, 1); PRIO0; \
    BAR(); \
    /* ph3: A(mh1) 8 reads; stage Hb+2 (B-lo slot; last read ph2) */ \
    RDA(T, 1, 0, 0); RDA(T, 1, 0, 1); RDA(T, 1, 1, 0); RDA(T, 1, 1, 1); \
    RDA(T, 1, 2, 0); RDA(T, 1, 2, 1); RDA(T, 1, 3, 0); RDA(T, 1, 3, 1); \
    stageH((Hbase) + 2); \
    BAR(); LGKM(0); \
    PRIO1; MQ(1, 0); PRIO0; \
    BAR(); \
    /* ph4: 0 reads; stage Hb+1, Hb+3 (A-slots; last read ph3); retire */ \
    stageH((Hbase) + 1); stageH((Hbase) + 3); \
    BAR(); \
    PRIO1; MQ(1, 1); PRIO0; \
    if (lastIt) { VMW(0); } else { VMW(6); } \
    BAR(); \
} while (0)

    TILE4(Ta, H0 + 7);
    TILE4(Tb, H0 + 11);
#undef TILE4
  }

#undef RDA
#undef RDB
#undef MQ

  // epilogue — C/D layout: col = lane&15, row = (lane>>4)*4 + j
#pragma unroll
  for (int am = 0; am < 8; ++am)
#pragma unroll
    for (int an = 0; an < 4; ++an)
#pragma unroll
      for (int j = 0; j < 4; ++j) {
        const long row = row0 + wr * 128 + am * 16 + klane * 4 + j;
        const long col = col0 + wc * 64 + an * 16 + rsel;
        out[row * N + col] = acc[am][an][j] + bias[col];
      }
}

// ---------------------------------------------------------------- launch

extern "C" void kernel_launch(void* const* d_in, const int* in_sizes, int n_in,
                              void* d_out, int out_size, void* d_ws, size_t ws_size,
                              hipStream_t stream) {
  (void)in_sizes; (void)n_in; (void)out_size; (void)ws_size;
  const float* x  = (const float*)d_in[0];
  const float* W  = (const float*)d_in[1];
  const float* b  = (const float*)d_in[2];
  const float* A  = (const float*)d_in[3];
  const float* B  = (const float*)d_in[4];
  const float* dw = (const float*)d_in[5];
  const int*   sd = (const int*)d_in[6];
  float* out = (float*)d_out;

  char* ws = (char*)d_ws;
  bf16* xb    = (bf16*)(ws);                          // 64 MB
  bf16* weff  = (bf16*)(ws + ((size_t)64 << 20));     // 32 MB
  bf16* bg    = (bf16*)(ws + ((size_t)96 << 20));     //  2 MB
  bf16* acatT = (bf16*)(ws + ((size_t)98 << 20));     //  2 MB

  // 1) fused memory-bound prep: x-cast | Bg | A^T
  prep_all_kernel<<<16384 + 4096 + 1024, 256, 0, stream>>>(
      x, xb, B, dw, sd, bg, A, acatT);

  // 2) W_eff = bf16(W + Bg @ AcatT^T)   : M=DOUT, N=DIN, K=256
  gemm_bt<<<(DOUT / 128) * (DIN / 128), 256, 0, stream>>>(
      bg, acatT, W, weff, DOUT, DIN, KLORA);

  // 3) out = xb @ W_eff^T + b           : M=T, N=DOUT, K=DIN
  static_assert((T_TOK % 256) == 0 && (DOUT % 256) == 0 && (DIN % 128) == 0, "");
  hipFuncSetAttribute(reinterpret_cast<const void*>(gemm256),
                      hipFuncAttributeMaxDynamicSharedMemorySize, 131072);
  gemm256<<<(T_TOK / 256) * (DOUT / 256), 512, 131072, stream>>>(
      xb, weff, b, out, T_TOK, DOUT, DIN);
}